// Round 9
// baseline (90.062 us; speedup 1.0000x reference)
//
#include <hip/hip_runtime.h>
#include <stdint.h>

#define HH 2048
#define WW 2048
#define TILE_W 64
#define TILE_H 32
#define HALO 3
#define ROWS_T (TILE_H + 2 * HALO)   // 38
#define LDSW 76                      // 72 cols used + 4 pad
#define HIST_BLOCK 256
#define HIST_GRID 2048               // 8 blocks/CU -> 100% occupancy
#define VPT 4                        // uint4 vectors per thread (64B in flight)
#define MAXBINS 4096

typedef float f4v __attribute__((ext_vector_type(4)));

// Monotone map: float bits -> uint32 such that uint order == float order.
__device__ __forceinline__ uint32_t map_f32(uint32_t b) {
    uint32_t mask = ((int32_t)b >> 31) | 0x80000000u;
    return b ^ mask;
}
__device__ __forceinline__ float unmap_f32(uint32_t u) {
    uint32_t b = (u & 0x80000000u) ? (u ^ 0x80000000u) : ~u;
    return __uint_as_float(b);
}

// state: [0]=prefix/median(mapped), [1]=k_remaining, [5]=candidate count
__global__ void init_kernel(uint32_t* hist, uint32_t* state, uint32_t k) {
    int i = blockIdx.x * blockDim.x + threadIdx.x;
    if (i < MAXBINS) hist[i] = 0;
    if (i < 8) state[i] = 0u;
    if (i == 1) state[1] = k;
}

// Level-0 histogram over top 12 bits; 4 independent uint4 loads in flight.
__global__ void __launch_bounds__(HIST_BLOCK)
hist_kernel(const uint4* __restrict__ in, int nvec,
            uint32_t* __restrict__ ghist) {
    __shared__ uint32_t lh[MAXBINS];
    int tid = threadIdx.x;
    for (int i = tid; i < MAXBINS; i += HIST_BLOCK) lh[i] = 0;
    __syncthreads();

    int total = HIST_GRID * HIST_BLOCK;
    int i0 = blockIdx.x * HIST_BLOCK + tid;

    if (nvec == total * VPT) {
        uint4 v[VPT];
        #pragma unroll
        for (int j = 0; j < VPT; ++j) v[j] = in[i0 + j * total];
        #pragma unroll
        for (int j = 0; j < VPT; ++j) {
            atomicAdd(&lh[map_f32(v[j].x) >> 20], 1u);
            atomicAdd(&lh[map_f32(v[j].y) >> 20], 1u);
            atomicAdd(&lh[map_f32(v[j].z) >> 20], 1u);
            atomicAdd(&lh[map_f32(v[j].w) >> 20], 1u);
        }
    } else {
        for (int i = i0; i < nvec; i += total) {
            uint4 v = in[i];
            atomicAdd(&lh[map_f32(v.x) >> 20], 1u);
            atomicAdd(&lh[map_f32(v.y) >> 20], 1u);
            atomicAdd(&lh[map_f32(v.z) >> 20], 1u);
            atomicAdd(&lh[map_f32(v.w) >> 20], 1u);
        }
    }
    __syncthreads();
    for (int b = tid; b < MAXBINS; b += HIST_BLOCK) {
        uint32_t s = lh[b];
        if (s) atomicAdd(&ghist[b], s);
    }
}

// Single block: pick the bucket containing rank k; state[0]=prefix, state[1]=rank in bucket.
__global__ void __launch_bounds__(256)
select_kernel(uint32_t* __restrict__ hist, uint32_t* __restrict__ state) {
    __shared__ uint32_t sums[256];
    int tid = threadIdx.x;
    uint32_t k = state[1];
    uint32_t local[16];
    uint32_t s = 0;
    #pragma unroll
    for (int i = 0; i < 16; ++i) {
        local[i] = hist[tid * 16 + i];
        s += local[i];
    }
    sums[tid] = s;
    __syncthreads();
    uint32_t excl = 0;
    for (int i = 0; i < tid; ++i) excl += sums[i];
    if (k >= excl && k < excl + s) {
        uint32_t cum = excl;
        #pragma unroll
        for (int i = 0; i < 16; ++i) {
            if (k >= cum && k < cum + local[i]) {
                state[0] = ((uint32_t)(tid * 16 + i)) << 20;
                state[1] = k - cum;
            }
            cum += local[i];
        }
    }
}

__device__ __forceinline__ void emit_cand(uint32_t u, uint32_t prefix, int lane,
                                          uint64_t lt, uint32_t* cand,
                                          uint32_t* counter) {
    bool p = (u & 0xFFF00000u) == prefix;
    uint64_t ball = __ballot(p);
    if (ball) {
        int leader = __ffsll((unsigned long long)ball) - 1;
        uint32_t base = 0;
        if (lane == leader) base = atomicAdd(counter, (uint32_t)__popcll(ball));
        base = __shfl(base, leader);
        if (p) cand[base + __popcll(ball & lt)] = u;
    }
}

// Compact all elements whose top-12 mapped bits equal the selected prefix.
__global__ void __launch_bounds__(HIST_BLOCK)
compact_kernel(const uint4* __restrict__ in, int nvec,
               uint32_t* __restrict__ cand,
               uint32_t* __restrict__ state) {
    uint32_t prefix = state[0];
    uint32_t* counter = &state[5];
    int total = HIST_GRID * HIST_BLOCK;
    int tid = threadIdx.x;
    int i0 = blockIdx.x * HIST_BLOCK + tid;
    int lane = tid & 63;
    uint64_t lt = ((uint64_t)1 << lane) - 1;

    if (nvec == total * VPT) {
        uint4 v[VPT];
        #pragma unroll
        for (int j = 0; j < VPT; ++j) v[j] = in[i0 + j * total];
        #pragma unroll
        for (int j = 0; j < VPT; ++j) {
            emit_cand(map_f32(v[j].x), prefix, lane, lt, cand, counter);
            emit_cand(map_f32(v[j].y), prefix, lane, lt, cand, counter);
            emit_cand(map_f32(v[j].z), prefix, lane, lt, cand, counter);
            emit_cand(map_f32(v[j].w), prefix, lane, lt, cand, counter);
        }
    } else {
        for (int i = i0; i < nvec; i += total) {
            uint4 v = in[i];
            emit_cand(map_f32(v.x), prefix, lane, lt, cand, counter);
            emit_cand(map_f32(v.y), prefix, lane, lt, cand, counter);
            emit_cand(map_f32(v.z), prefix, lane, lt, cand, counter);
            emit_cand(map_f32(v.w), prefix, lane, lt, cand, counter);
        }
    }
}

// Single block: exact k-th smallest among candidates (two radix passes in LDS).
__global__ void __launch_bounds__(1024)
final_select_kernel(const uint32_t* __restrict__ cand,
                    uint32_t* __restrict__ state) {
    __shared__ uint32_t lh[MAXBINS];
    __shared__ uint32_t sums[256];
    __shared__ uint32_t s_prefix, s_k;
    int tid = threadIdx.x;
    uint32_t C = state[5];

    if (tid == 0) { s_prefix = state[0]; s_k = state[1]; }
    for (int i = tid; i < MAXBINS; i += 1024) lh[i] = 0;
    __syncthreads();

    // Pass A: bits [8,20)
    for (uint32_t i = tid; i < C; i += 1024)
        atomicAdd(&lh[(cand[i] >> 8) & 4095u], 1u);
    __syncthreads();
    if (tid < 256) {
        uint32_t local[16];
        uint32_t s = 0;
        #pragma unroll
        for (int i = 0; i < 16; ++i) { local[i] = lh[tid * 16 + i]; s += local[i]; }
        sums[tid] = s;
    }
    __syncthreads();
    if (tid < 256) {
        uint32_t local[16];
        uint32_t s = 0;
        #pragma unroll
        for (int i = 0; i < 16; ++i) { local[i] = lh[tid * 16 + i]; s += local[i]; }
        uint32_t excl = 0;
        for (int i = 0; i < tid; ++i) excl += sums[i];
        uint32_t k = s_k;
        if (k >= excl && k < excl + s) {
            uint32_t cum = excl;
            #pragma unroll
            for (int i = 0; i < 16; ++i) {
                if (k >= cum && k < cum + local[i]) {
                    s_prefix |= ((uint32_t)(tid * 16 + i)) << 8;
                    s_k = k - cum;
                }
                cum += local[i];
            }
        }
    }
    __syncthreads();

    // Pass B: bits [0,8)
    for (int i = tid; i < 256; i += 1024) lh[i] = 0;
    __syncthreads();
    uint32_t pfx = s_prefix;
    for (uint32_t i = tid; i < C; i += 1024) {
        uint32_t u = cand[i];
        if ((u & 0xFFFFFF00u) == pfx) atomicAdd(&lh[u & 255u], 1u);
    }
    __syncthreads();
    if (tid < 256) {
        uint32_t cnt = lh[tid];
        sums[tid] = cnt;
    }
    __syncthreads();
    if (tid < 256) {
        uint32_t cnt = sums[tid];
        uint32_t excl = 0;
        for (int i = 0; i < tid; ++i) excl += sums[i];
        uint32_t k = s_k;
        if (k >= excl && k < excl + cnt) {
            state[0] = pfx | (uint32_t)tid;   // exact mapped median
        }
    }
}

// Fused threshold + 7x7 maxpool (separable) + compare + write.
// 64x32 output tile, 21.4 KB LDS -> 7 blocks/CU.
// Compare vs thresholded center from LDS (no x re-read):
//   out = (pooled == tc && tc != 0) ? tc : 0  == reference.
// Non-temporal stores: output is write-once, keep x resident in L3.
__global__ void __launch_bounds__(256)
nms_kernel(const float* __restrict__ x, float* __restrict__ out,
           const uint32_t* __restrict__ state) {
    __shared__ float t_lds[ROWS_T][LDSW];        // 38 x 76
    __shared__ float h_lds[ROWS_T][TILE_W + 1];  // 38 x 65
    float med = unmap_f32(state[0]);

    int plane = blockIdx.z;
    int tr0 = blockIdx.y * TILE_H;
    int tc0 = blockIdx.x * TILE_W;
    const float* px = x + (size_t)plane * HH * WW;
    float* pout = out + (size_t)plane * HH * WW;
    int tid = threadIdx.x;

    bool interior = (blockIdx.x >= 1) && (blockIdx.x <= (WW / TILE_W) - 2) &&
                    (blockIdx.y >= 1) && (blockIdx.y <= (HH / TILE_H) - 2);
    if (interior) {
        const float4* pv = (const float4*)(px + (size_t)(tr0 - 3) * WW + (tc0 - 4));
        for (int i = tid; i < ROWS_T * 18; i += 256) {
            int r = i / 18, v = i - r * 18;
            float4 d = pv[(size_t)r * (WW / 4) + v];
            int c = v * 4;
            t_lds[r][c + 0] = (d.x < med) ? 0.f : d.x;
            t_lds[r][c + 1] = (d.y < med) ? 0.f : d.y;
            t_lds[r][c + 2] = (d.z < med) ? 0.f : d.z;
            t_lds[r][c + 3] = (d.w < med) ? 0.f : d.w;
        }
    } else {
        for (int i = tid; i < ROWS_T * 72; i += 256) {
            int r = i / 72, c = i - r * 72;
            int gr = tr0 - 3 + r, gc = tc0 - 4 + c;
            float vv = -INFINITY;
            if (gr >= 0 && gr < HH && gc >= 0 && gc < WW) {
                float xv = px[(size_t)gr * WW + gc];
                vv = (xv < med) ? 0.f : xv;
            }
            t_lds[r][c] = vv;
        }
    }
    __syncthreads();

    // Horizontal 7-max: output col c uses lds cols c+1 .. c+7
    for (int i = tid; i < ROWS_T * TILE_W; i += 256) {
        int r = i >> 6, c = i & 63;
        float m = t_lds[r][c + 1];
        #pragma unroll
        for (int j = 2; j <= 7; ++j) m = fmaxf(m, t_lds[r][c + j]);
        h_lds[r][c] = m;
    }
    __syncthreads();

    // Vertical 7-max + compare vs thresholded center + NT float4 store
    for (int i = tid; i < TILE_H * (TILE_W / 4); i += 256) {
        int r = i >> 4, c4 = (i & 15) * 4;
        float m0 = h_lds[r][c4 + 0], m1 = h_lds[r][c4 + 1];
        float m2 = h_lds[r][c4 + 2], m3 = h_lds[r][c4 + 3];
        #pragma unroll
        for (int j = 1; j < 7; ++j) {
            m0 = fmaxf(m0, h_lds[r + j][c4 + 0]);
            m1 = fmaxf(m1, h_lds[r + j][c4 + 1]);
            m2 = fmaxf(m2, h_lds[r + j][c4 + 2]);
            m3 = fmaxf(m3, h_lds[r + j][c4 + 3]);
        }
        float t0 = t_lds[r + 3][c4 + 4], t1 = t_lds[r + 3][c4 + 5];
        float t2 = t_lds[r + 3][c4 + 6], t3 = t_lds[r + 3][c4 + 7];
        f4v o;
        o.x = (m0 == t0 && t0 != 0.f) ? t0 : 0.f;
        o.y = (m1 == t1 && t1 != 0.f) ? t1 : 0.f;
        o.z = (m2 == t2 && t2 != 0.f) ? t2 : 0.f;
        o.w = (m3 == t3 && t3 != 0.f) ? t3 : 0.f;
        __builtin_nontemporal_store(o, (f4v*)(pout + (size_t)(tr0 + r) * WW + (tc0 + c4)));
    }
}

extern "C" void kernel_launch(void* const* d_in, const int* in_sizes, int n_in,
                              void* d_out, int out_size, void* d_ws, size_t ws_size,
                              hipStream_t stream) {
    const float* x = (const float*)d_in[0];
    float* out = (float*)d_out;
    int n = in_sizes[0];                    // 8388608
    uint32_t* hist = (uint32_t*)d_ws;       // 4096 u32
    uint32_t* state = hist + MAXBINS;       // 8 u32
    uint32_t* cand = state + 8;             // candidates (mapped u32)
    uint32_t k = (uint32_t)((n - 1) / 2);
    int nvec = n / 4;

    init_kernel<<<16, 256, 0, stream>>>(hist, state, k);
    hist_kernel<<<HIST_GRID, HIST_BLOCK, 0, stream>>>((const uint4*)x, nvec, hist);
    select_kernel<<<1, 256, 0, stream>>>(hist, state);
    compact_kernel<<<HIST_GRID, HIST_BLOCK, 0, stream>>>((const uint4*)x, nvec, cand, state);
    final_select_kernel<<<1, 1024, 0, stream>>>(cand, state);

    int nplanes = n / (HH * WW);            // 2
    dim3 grid(WW / TILE_W, HH / TILE_H, nplanes);
    nms_kernel<<<grid, 256, 0, stream>>>(x, out, state);
}

// Round 10
// 71.981 us; speedup vs baseline: 1.2512x; 1.2512x over previous
//
#include <hip/hip_runtime.h>
#include <stdint.h>

#define HH 2048
#define WW 2048
#define TILE_W 64
#define TILE_H 32
#define HALO 3
#define ROWS_T (TILE_H + 2 * HALO)   // 38
#define LDSW 76                      // 72 cols used + 4 pad
#define HIST_BLOCK 256
#define HIST_GRID 1024               // hist: proven config (VPT=8, 8-deep MLP)
#define HVPT 8
#define COMP_GRID 2048               // compact: L3-hot read, 4-deep suffices
#define CVPT 4
#define MAXBINS 4096

typedef float f4v __attribute__((ext_vector_type(4)));

// Monotone map: float bits -> uint32 such that uint order == float order.
__device__ __forceinline__ uint32_t map_f32(uint32_t b) {
    uint32_t mask = ((int32_t)b >> 31) | 0x80000000u;
    return b ^ mask;
}
__device__ __forceinline__ float unmap_f32(uint32_t u) {
    uint32_t b = (u & 0x80000000u) ? (u ^ 0x80000000u) : ~u;
    return __uint_as_float(b);
}

// state: [0]=prefix/median(mapped), [1]=k_remaining, [5]=candidate count
__global__ void init_kernel(uint32_t* hist, uint32_t* state, uint32_t k) {
    int i = blockIdx.x * blockDim.x + threadIdx.x;
    if (i < MAXBINS) hist[i] = 0;
    if (i < 8) state[i] = 0u;
    if (i == 1) state[1] = k;
}

// Level-0 histogram over top 12 bits; 8 independent uint4 loads in flight.
__global__ void __launch_bounds__(HIST_BLOCK)
hist_kernel(const uint4* __restrict__ in, int nvec,
            uint32_t* __restrict__ ghist) {
    __shared__ uint32_t lh[MAXBINS];
    int tid = threadIdx.x;
    for (int i = tid; i < MAXBINS; i += HIST_BLOCK) lh[i] = 0;
    __syncthreads();

    int total = HIST_GRID * HIST_BLOCK;
    int i0 = blockIdx.x * HIST_BLOCK + tid;

    if (nvec == total * HVPT) {
        uint4 v[HVPT];
        #pragma unroll
        for (int j = 0; j < HVPT; ++j) v[j] = in[i0 + j * total];
        #pragma unroll
        for (int j = 0; j < HVPT; ++j) {
            atomicAdd(&lh[map_f32(v[j].x) >> 20], 1u);
            atomicAdd(&lh[map_f32(v[j].y) >> 20], 1u);
            atomicAdd(&lh[map_f32(v[j].z) >> 20], 1u);
            atomicAdd(&lh[map_f32(v[j].w) >> 20], 1u);
        }
    } else {
        for (int i = i0; i < nvec; i += total) {
            uint4 v = in[i];
            atomicAdd(&lh[map_f32(v.x) >> 20], 1u);
            atomicAdd(&lh[map_f32(v.y) >> 20], 1u);
            atomicAdd(&lh[map_f32(v.z) >> 20], 1u);
            atomicAdd(&lh[map_f32(v.w) >> 20], 1u);
        }
    }
    __syncthreads();
    for (int b = tid; b < MAXBINS; b += HIST_BLOCK) {
        uint32_t s = lh[b];
        if (s) atomicAdd(&ghist[b], s);
    }
}

// Single block: pick the bucket containing rank k; state[0]=prefix, state[1]=rank in bucket.
__global__ void __launch_bounds__(256)
select_kernel(uint32_t* __restrict__ hist, uint32_t* __restrict__ state) {
    __shared__ uint32_t sums[256];
    int tid = threadIdx.x;
    uint32_t k = state[1];
    uint32_t local[16];
    uint32_t s = 0;
    #pragma unroll
    for (int i = 0; i < 16; ++i) {
        local[i] = hist[tid * 16 + i];
        s += local[i];
    }
    sums[tid] = s;
    __syncthreads();
    uint32_t excl = 0;
    for (int i = 0; i < tid; ++i) excl += sums[i];
    if (k >= excl && k < excl + s) {
        uint32_t cum = excl;
        #pragma unroll
        for (int i = 0; i < 16; ++i) {
            if (k >= cum && k < cum + local[i]) {
                state[0] = ((uint32_t)(tid * 16 + i)) << 20;
                state[1] = k - cum;
            }
            cum += local[i];
        }
    }
}

__device__ __forceinline__ void emit_cand(uint32_t u, uint32_t prefix, int lane,
                                          uint64_t lt, uint32_t* cand,
                                          uint32_t* counter) {
    bool p = (u & 0xFFF00000u) == prefix;
    uint64_t ball = __ballot(p);
    if (ball) {
        int leader = __ffsll((unsigned long long)ball) - 1;
        uint32_t base = 0;
        if (lane == leader) base = atomicAdd(counter, (uint32_t)__popcll(ball));
        base = __shfl(base, leader);
        if (p) cand[base + __popcll(ball & lt)] = u;
    }
}

// Compact all elements whose top-12 mapped bits equal the selected prefix.
__global__ void __launch_bounds__(HIST_BLOCK)
compact_kernel(const uint4* __restrict__ in, int nvec,
               uint32_t* __restrict__ cand,
               uint32_t* __restrict__ state) {
    uint32_t prefix = state[0];
    uint32_t* counter = &state[5];
    int total = COMP_GRID * HIST_BLOCK;
    int tid = threadIdx.x;
    int i0 = blockIdx.x * HIST_BLOCK + tid;
    int lane = tid & 63;
    uint64_t lt = ((uint64_t)1 << lane) - 1;

    if (nvec == total * CVPT) {
        uint4 v[CVPT];
        #pragma unroll
        for (int j = 0; j < CVPT; ++j) v[j] = in[i0 + j * total];
        #pragma unroll
        for (int j = 0; j < CVPT; ++j) {
            emit_cand(map_f32(v[j].x), prefix, lane, lt, cand, counter);
            emit_cand(map_f32(v[j].y), prefix, lane, lt, cand, counter);
            emit_cand(map_f32(v[j].z), prefix, lane, lt, cand, counter);
            emit_cand(map_f32(v[j].w), prefix, lane, lt, cand, counter);
        }
    } else {
        for (int i = i0; i < nvec; i += total) {
            uint4 v = in[i];
            emit_cand(map_f32(v.x), prefix, lane, lt, cand, counter);
            emit_cand(map_f32(v.y), prefix, lane, lt, cand, counter);
            emit_cand(map_f32(v.z), prefix, lane, lt, cand, counter);
            emit_cand(map_f32(v.w), prefix, lane, lt, cand, counter);
        }
    }
}

// Single block: exact k-th smallest among candidates (two radix passes in LDS).
__global__ void __launch_bounds__(1024)
final_select_kernel(const uint32_t* __restrict__ cand,
                    uint32_t* __restrict__ state) {
    __shared__ uint32_t lh[MAXBINS];
    __shared__ uint32_t sums[256];
    __shared__ uint32_t s_prefix, s_k;
    int tid = threadIdx.x;
    uint32_t C = state[5];

    if (tid == 0) { s_prefix = state[0]; s_k = state[1]; }
    for (int i = tid; i < MAXBINS; i += 1024) lh[i] = 0;
    __syncthreads();

    // Pass A: bits [8,20)
    for (uint32_t i = tid; i < C; i += 1024)
        atomicAdd(&lh[(cand[i] >> 8) & 4095u], 1u);
    __syncthreads();
    if (tid < 256) {
        uint32_t local[16];
        uint32_t s = 0;
        #pragma unroll
        for (int i = 0; i < 16; ++i) { local[i] = lh[tid * 16 + i]; s += local[i]; }
        sums[tid] = s;
    }
    __syncthreads();
    if (tid < 256) {
        uint32_t local[16];
        uint32_t s = 0;
        #pragma unroll
        for (int i = 0; i < 16; ++i) { local[i] = lh[tid * 16 + i]; s += local[i]; }
        uint32_t excl = 0;
        for (int i = 0; i < tid; ++i) excl += sums[i];
        uint32_t k = s_k;
        if (k >= excl && k < excl + s) {
            uint32_t cum = excl;
            #pragma unroll
            for (int i = 0; i < 16; ++i) {
                if (k >= cum && k < cum + local[i]) {
                    s_prefix |= ((uint32_t)(tid * 16 + i)) << 8;
                    s_k = k - cum;
                }
                cum += local[i];
            }
        }
    }
    __syncthreads();

    // Pass B: bits [0,8)
    for (int i = tid; i < 256; i += 1024) lh[i] = 0;
    __syncthreads();
    uint32_t pfx = s_prefix;
    for (uint32_t i = tid; i < C; i += 1024) {
        uint32_t u = cand[i];
        if ((u & 0xFFFFFF00u) == pfx) atomicAdd(&lh[u & 255u], 1u);
    }
    __syncthreads();
    if (tid < 256) {
        uint32_t cnt = lh[tid];
        sums[tid] = cnt;
    }
    __syncthreads();
    if (tid < 256) {
        uint32_t cnt = sums[tid];
        uint32_t excl = 0;
        for (int i = 0; i < tid; ++i) excl += sums[i];
        uint32_t k = s_k;
        if (k >= excl && k < excl + cnt) {
            state[0] = pfx | (uint32_t)tid;   // exact mapped median
        }
    }
}

// Fused threshold + 7x7 maxpool (separable) + compare + write.
// 64x32 output tile, 21.4 KB LDS -> 7 blocks/CU.
// Compare vs thresholded center from LDS (no x re-read):
//   out = (pooled == tc && tc != 0) ? tc : 0  == reference.
// Non-temporal stores: output is write-once, keep x resident in L3.
__global__ void __launch_bounds__(256)
nms_kernel(const float* __restrict__ x, float* __restrict__ out,
           const uint32_t* __restrict__ state) {
    __shared__ float t_lds[ROWS_T][LDSW];        // 38 x 76
    __shared__ float h_lds[ROWS_T][TILE_W + 1];  // 38 x 65
    float med = unmap_f32(state[0]);

    int plane = blockIdx.z;
    int tr0 = blockIdx.y * TILE_H;
    int tc0 = blockIdx.x * TILE_W;
    const float* px = x + (size_t)plane * HH * WW;
    float* pout = out + (size_t)plane * HH * WW;
    int tid = threadIdx.x;

    bool interior = (blockIdx.x >= 1) && (blockIdx.x <= (WW / TILE_W) - 2) &&
                    (blockIdx.y >= 1) && (blockIdx.y <= (HH / TILE_H) - 2);
    if (interior) {
        const float4* pv = (const float4*)(px + (size_t)(tr0 - 3) * WW + (tc0 - 4));
        for (int i = tid; i < ROWS_T * 18; i += 256) {
            int r = i / 18, v = i - r * 18;
            float4 d = pv[(size_t)r * (WW / 4) + v];
            int c = v * 4;
            t_lds[r][c + 0] = (d.x < med) ? 0.f : d.x;
            t_lds[r][c + 1] = (d.y < med) ? 0.f : d.y;
            t_lds[r][c + 2] = (d.z < med) ? 0.f : d.z;
            t_lds[r][c + 3] = (d.w < med) ? 0.f : d.w;
        }
    } else {
        for (int i = tid; i < ROWS_T * 72; i += 256) {
            int r = i / 72, c = i - r * 72;
            int gr = tr0 - 3 + r, gc = tc0 - 4 + c;
            float vv = -INFINITY;
            if (gr >= 0 && gr < HH && gc >= 0 && gc < WW) {
                float xv = px[(size_t)gr * WW + gc];
                vv = (xv < med) ? 0.f : xv;
            }
            t_lds[r][c] = vv;
        }
    }
    __syncthreads();

    // Horizontal 7-max: output col c uses lds cols c+1 .. c+7
    for (int i = tid; i < ROWS_T * TILE_W; i += 256) {
        int r = i >> 6, c = i & 63;
        float m = t_lds[r][c + 1];
        #pragma unroll
        for (int j = 2; j <= 7; ++j) m = fmaxf(m, t_lds[r][c + j]);
        h_lds[r][c] = m;
    }
    __syncthreads();

    // Vertical 7-max + compare vs thresholded center + NT float4 store
    for (int i = tid; i < TILE_H * (TILE_W / 4); i += 256) {
        int r = i >> 4, c4 = (i & 15) * 4;
        float m0 = h_lds[r][c4 + 0], m1 = h_lds[r][c4 + 1];
        float m2 = h_lds[r][c4 + 2], m3 = h_lds[r][c4 + 3];
        #pragma unroll
        for (int j = 1; j < 7; ++j) {
            m0 = fmaxf(m0, h_lds[r + j][c4 + 0]);
            m1 = fmaxf(m1, h_lds[r + j][c4 + 1]);
            m2 = fmaxf(m2, h_lds[r + j][c4 + 2]);
            m3 = fmaxf(m3, h_lds[r + j][c4 + 3]);
        }
        float t0 = t_lds[r + 3][c4 + 4], t1 = t_lds[r + 3][c4 + 5];
        float t2 = t_lds[r + 3][c4 + 6], t3 = t_lds[r + 3][c4 + 7];
        f4v o;
        o.x = (m0 == t0 && t0 != 0.f) ? t0 : 0.f;
        o.y = (m1 == t1 && t1 != 0.f) ? t1 : 0.f;
        o.z = (m2 == t2 && t2 != 0.f) ? t2 : 0.f;
        o.w = (m3 == t3 && t3 != 0.f) ? t3 : 0.f;
        __builtin_nontemporal_store(o, (f4v*)(pout + (size_t)(tr0 + r) * WW + (tc0 + c4)));
    }
}

extern "C" void kernel_launch(void* const* d_in, const int* in_sizes, int n_in,
                              void* d_out, int out_size, void* d_ws, size_t ws_size,
                              hipStream_t stream) {
    const float* x = (const float*)d_in[0];
    float* out = (float*)d_out;
    int n = in_sizes[0];                    // 8388608
    uint32_t* hist = (uint32_t*)d_ws;       // 4096 u32
    uint32_t* state = hist + MAXBINS;       // 8 u32
    uint32_t* cand = state + 8;             // candidates (mapped u32)
    uint32_t k = (uint32_t)((n - 1) / 2);
    int nvec = n / 4;

    init_kernel<<<16, 256, 0, stream>>>(hist, state, k);
    hist_kernel<<<HIST_GRID, HIST_BLOCK, 0, stream>>>((const uint4*)x, nvec, hist);
    select_kernel<<<1, 256, 0, stream>>>(hist, state);
    compact_kernel<<<COMP_GRID, HIST_BLOCK, 0, stream>>>((const uint4*)x, nvec, cand, state);
    final_select_kernel<<<1, 1024, 0, stream>>>(cand, state);

    int nplanes = n / (HH * WW);            // 2
    dim3 grid(WW / TILE_W, HH / TILE_H, nplanes);
    nms_kernel<<<grid, 256, 0, stream>>>(x, out, state);
}

// Round 11
// 58.475 us; speedup vs baseline: 1.5402x; 1.2310x over previous
//
#include <hip/hip_runtime.h>
#include <stdint.h>

#define HH 2048
#define WW 2048
#define TILE_W 64
#define TILE_H 32
#define HALO 3
#define ROWS_T (TILE_H + 2 * HALO)   // 38
#define LDSW 76                      // 72 cols used + 4 pad
#define HIST_BLOCK 256
#define HIST_GRID 1024               // hist: proven config (VPT=8, 8-deep MLP)
#define HVPT 8
#define COMP_GRID 2048               // compact: L3-hot read, 4-deep suffices
#define CVPT 4
#define MAXBINS 4096
#define HSPREAD 16                   // flush-contention spread (slot-major)

typedef float f4v __attribute__((ext_vector_type(4)));

// Monotone map: float bits -> uint32 such that uint order == float order.
__device__ __forceinline__ uint32_t map_f32(uint32_t b) {
    uint32_t mask = ((int32_t)b >> 31) | 0x80000000u;
    return b ^ mask;
}
__device__ __forceinline__ float unmap_f32(uint32_t u) {
    uint32_t b = (u & 0x80000000u) ? (u ^ 0x80000000u) : ~u;
    return __uint_as_float(b);
}

// state: [0]=prefix/median(mapped), [1]=k_remaining, [5]=candidate count
__global__ void init_kernel(uint32_t* hist, uint32_t* state, uint32_t k) {
    int i = blockIdx.x * blockDim.x + threadIdx.x;
    if (i < MAXBINS * HSPREAD) hist[i] = 0;
    if (i < 8) state[i] = 0u;
    if (i == 1) state[1] = k;
}

// Level-0 histogram over top 12 bits; 8 independent uint4 loads in flight.
// Flush spreads each bin over HSPREAD slot-major copies (16 KB apart) to cut
// per-address device-atomic serialization from 1024 to 64 contenders.
__global__ void __launch_bounds__(HIST_BLOCK)
hist_kernel(const uint4* __restrict__ in, int nvec,
            uint32_t* __restrict__ ghist) {
    __shared__ uint32_t lh[MAXBINS];
    int tid = threadIdx.x;
    for (int i = tid; i < MAXBINS; i += HIST_BLOCK) lh[i] = 0;
    __syncthreads();

    int total = HIST_GRID * HIST_BLOCK;
    int i0 = blockIdx.x * HIST_BLOCK + tid;

    if (nvec == total * HVPT) {
        uint4 v[HVPT];
        #pragma unroll
        for (int j = 0; j < HVPT; ++j) v[j] = in[i0 + j * total];
        #pragma unroll
        for (int j = 0; j < HVPT; ++j) {
            atomicAdd(&lh[map_f32(v[j].x) >> 20], 1u);
            atomicAdd(&lh[map_f32(v[j].y) >> 20], 1u);
            atomicAdd(&lh[map_f32(v[j].z) >> 20], 1u);
            atomicAdd(&lh[map_f32(v[j].w) >> 20], 1u);
        }
    } else {
        for (int i = i0; i < nvec; i += total) {
            uint4 v = in[i];
            atomicAdd(&lh[map_f32(v.x) >> 20], 1u);
            atomicAdd(&lh[map_f32(v.y) >> 20], 1u);
            atomicAdd(&lh[map_f32(v.z) >> 20], 1u);
            atomicAdd(&lh[map_f32(v.w) >> 20], 1u);
        }
    }
    __syncthreads();
    int slot = blockIdx.x & (HSPREAD - 1);
    uint32_t* gslot = ghist + (size_t)slot * MAXBINS;
    for (int b = tid; b < MAXBINS; b += HIST_BLOCK) {
        uint32_t s = lh[b];
        if (s) atomicAdd(&gslot[b], s);
    }
}

// Single block: sum the HSPREAD slot copies, pick the bucket containing rank k.
__global__ void __launch_bounds__(256)
select_kernel(uint32_t* __restrict__ hist, uint32_t* __restrict__ state) {
    __shared__ uint32_t sums[256];
    int tid = threadIdx.x;
    uint32_t k = state[1];
    uint32_t local[16];
    #pragma unroll
    for (int i = 0; i < 16; ++i) local[i] = 0;
    for (int sp = 0; sp < HSPREAD; ++sp) {
        const uint32_t* h = hist + (size_t)sp * MAXBINS + tid * 16;
        #pragma unroll
        for (int i = 0; i < 16; ++i) local[i] += h[i];
    }
    uint32_t s = 0;
    #pragma unroll
    for (int i = 0; i < 16; ++i) s += local[i];
    sums[tid] = s;
    __syncthreads();
    uint32_t excl = 0;
    for (int i = 0; i < tid; ++i) excl += sums[i];
    if (k >= excl && k < excl + s) {
        uint32_t cum = excl;
        #pragma unroll
        for (int i = 0; i < 16; ++i) {
            if (k >= cum && k < cum + local[i]) {
                state[0] = ((uint32_t)(tid * 16 + i)) << 20;
                state[1] = k - cum;
            }
            cum += local[i];
        }
    }
}

__device__ __forceinline__ void emit_cand(uint32_t u, uint32_t prefix, int lane,
                                          uint64_t lt, uint32_t* cand,
                                          uint32_t* counter) {
    bool p = (u & 0xFFF00000u) == prefix;
    uint64_t ball = __ballot(p);
    if (ball) {
        int leader = __ffsll((unsigned long long)ball) - 1;
        uint32_t base = 0;
        if (lane == leader) base = atomicAdd(counter, (uint32_t)__popcll(ball));
        base = __shfl(base, leader);
        if (p) cand[base + __popcll(ball & lt)] = u;
    }
}

// Compact all elements whose top-12 mapped bits equal the selected prefix.
__global__ void __launch_bounds__(HIST_BLOCK)
compact_kernel(const uint4* __restrict__ in, int nvec,
               uint32_t* __restrict__ cand,
               uint32_t* __restrict__ state) {
    uint32_t prefix = state[0];
    uint32_t* counter = &state[5];
    int total = COMP_GRID * HIST_BLOCK;
    int tid = threadIdx.x;
    int i0 = blockIdx.x * HIST_BLOCK + tid;
    int lane = tid & 63;
    uint64_t lt = ((uint64_t)1 << lane) - 1;

    if (nvec == total * CVPT) {
        uint4 v[CVPT];
        #pragma unroll
        for (int j = 0; j < CVPT; ++j) v[j] = in[i0 + j * total];
        #pragma unroll
        for (int j = 0; j < CVPT; ++j) {
            emit_cand(map_f32(v[j].x), prefix, lane, lt, cand, counter);
            emit_cand(map_f32(v[j].y), prefix, lane, lt, cand, counter);
            emit_cand(map_f32(v[j].z), prefix, lane, lt, cand, counter);
            emit_cand(map_f32(v[j].w), prefix, lane, lt, cand, counter);
        }
    } else {
        for (int i = i0; i < nvec; i += total) {
            uint4 v = in[i];
            emit_cand(map_f32(v.x), prefix, lane, lt, cand, counter);
            emit_cand(map_f32(v.y), prefix, lane, lt, cand, counter);
            emit_cand(map_f32(v.z), prefix, lane, lt, cand, counter);
            emit_cand(map_f32(v.w), prefix, lane, lt, cand, counter);
        }
    }
}

// Single block: exact k-th smallest among candidates (two radix passes in LDS).
__global__ void __launch_bounds__(1024)
final_select_kernel(const uint32_t* __restrict__ cand,
                    uint32_t* __restrict__ state) {
    __shared__ uint32_t lh[MAXBINS];
    __shared__ uint32_t sums[256];
    __shared__ uint32_t s_prefix, s_k;
    int tid = threadIdx.x;
    uint32_t C = state[5];

    if (tid == 0) { s_prefix = state[0]; s_k = state[1]; }
    for (int i = tid; i < MAXBINS; i += 1024) lh[i] = 0;
    __syncthreads();

    // Pass A: bits [8,20)
    for (uint32_t i = tid; i < C; i += 1024)
        atomicAdd(&lh[(cand[i] >> 8) & 4095u], 1u);
    __syncthreads();
    if (tid < 256) {
        uint32_t local[16];
        uint32_t s = 0;
        #pragma unroll
        for (int i = 0; i < 16; ++i) { local[i] = lh[tid * 16 + i]; s += local[i]; }
        sums[tid] = s;
    }
    __syncthreads();
    if (tid < 256) {
        uint32_t local[16];
        uint32_t s = 0;
        #pragma unroll
        for (int i = 0; i < 16; ++i) { local[i] = lh[tid * 16 + i]; s += local[i]; }
        uint32_t excl = 0;
        for (int i = 0; i < tid; ++i) excl += sums[i];
        uint32_t k = s_k;
        if (k >= excl && k < excl + s) {
            uint32_t cum = excl;
            #pragma unroll
            for (int i = 0; i < 16; ++i) {
                if (k >= cum && k < cum + local[i]) {
                    s_prefix |= ((uint32_t)(tid * 16 + i)) << 8;
                    s_k = k - cum;
                }
                cum += local[i];
            }
        }
    }
    __syncthreads();

    // Pass B: bits [0,8)
    for (int i = tid; i < 256; i += 1024) lh[i] = 0;
    __syncthreads();
    uint32_t pfx = s_prefix;
    for (uint32_t i = tid; i < C; i += 1024) {
        uint32_t u = cand[i];
        if ((u & 0xFFFFFF00u) == pfx) atomicAdd(&lh[u & 255u], 1u);
    }
    __syncthreads();
    if (tid < 256) {
        uint32_t cnt = lh[tid];
        sums[tid] = cnt;
    }
    __syncthreads();
    if (tid < 256) {
        uint32_t cnt = sums[tid];
        uint32_t excl = 0;
        for (int i = 0; i < tid; ++i) excl += sums[i];
        uint32_t k = s_k;
        if (k >= excl && k < excl + cnt) {
            state[0] = pfx | (uint32_t)tid;   // exact mapped median
        }
    }
}

// Fused threshold + 7x7 maxpool (separable) + compare + write.
// 64x32 output tile, 21.4 KB LDS -> 7 blocks/CU.
// Compare vs thresholded center from LDS (no x re-read):
//   out = (pooled == tc && tc != 0) ? tc : 0  == reference.
__global__ void __launch_bounds__(256)
nms_kernel(const float* __restrict__ x, float* __restrict__ out,
           const uint32_t* __restrict__ state) {
    __shared__ float t_lds[ROWS_T][LDSW];        // 38 x 76
    __shared__ float h_lds[ROWS_T][TILE_W + 1];  // 38 x 65
    float med = unmap_f32(state[0]);

    int plane = blockIdx.z;
    int tr0 = blockIdx.y * TILE_H;
    int tc0 = blockIdx.x * TILE_W;
    const float* px = x + (size_t)plane * HH * WW;
    float* pout = out + (size_t)plane * HH * WW;
    int tid = threadIdx.x;

    bool interior = (blockIdx.x >= 1) && (blockIdx.x <= (WW / TILE_W) - 2) &&
                    (blockIdx.y >= 1) && (blockIdx.y <= (HH / TILE_H) - 2);
    if (interior) {
        const float4* pv = (const float4*)(px + (size_t)(tr0 - 3) * WW + (tc0 - 4));
        for (int i = tid; i < ROWS_T * 18; i += 256) {
            int r = i / 18, v = i - r * 18;
            float4 d = pv[(size_t)r * (WW / 4) + v];
            int c = v * 4;
            t_lds[r][c + 0] = (d.x < med) ? 0.f : d.x;
            t_lds[r][c + 1] = (d.y < med) ? 0.f : d.y;
            t_lds[r][c + 2] = (d.z < med) ? 0.f : d.z;
            t_lds[r][c + 3] = (d.w < med) ? 0.f : d.w;
        }
    } else {
        for (int i = tid; i < ROWS_T * 72; i += 256) {
            int r = i / 72, c = i - r * 72;
            int gr = tr0 - 3 + r, gc = tc0 - 4 + c;
            float vv = -INFINITY;
            if (gr >= 0 && gr < HH && gc >= 0 && gc < WW) {
                float xv = px[(size_t)gr * WW + gc];
                vv = (xv < med) ? 0.f : xv;
            }
            t_lds[r][c] = vv;
        }
    }
    __syncthreads();

    // Horizontal 7-max: output col c uses lds cols c+1 .. c+7
    for (int i = tid; i < ROWS_T * TILE_W; i += 256) {
        int r = i >> 6, c = i & 63;
        float m = t_lds[r][c + 1];
        #pragma unroll
        for (int j = 2; j <= 7; ++j) m = fmaxf(m, t_lds[r][c + j]);
        h_lds[r][c] = m;
    }
    __syncthreads();

    // Vertical 7-max + compare vs thresholded center + NT float4 store
    for (int i = tid; i < TILE_H * (TILE_W / 4); i += 256) {
        int r = i >> 4, c4 = (i & 15) * 4;
        float m0 = h_lds[r][c4 + 0], m1 = h_lds[r][c4 + 1];
        float m2 = h_lds[r][c4 + 2], m3 = h_lds[r][c4 + 3];
        #pragma unroll
        for (int j = 1; j < 7; ++j) {
            m0 = fmaxf(m0, h_lds[r + j][c4 + 0]);
            m1 = fmaxf(m1, h_lds[r + j][c4 + 1]);
            m2 = fmaxf(m2, h_lds[r + j][c4 + 2]);
            m3 = fmaxf(m3, h_lds[r + j][c4 + 3]);
        }
        float t0 = t_lds[r + 3][c4 + 4], t1 = t_lds[r + 3][c4 + 5];
        float t2 = t_lds[r + 3][c4 + 6], t3 = t_lds[r + 3][c4 + 7];
        f4v o;
        o.x = (m0 == t0 && t0 != 0.f) ? t0 : 0.f;
        o.y = (m1 == t1 && t1 != 0.f) ? t1 : 0.f;
        o.z = (m2 == t2 && t2 != 0.f) ? t2 : 0.f;
        o.w = (m3 == t3 && t3 != 0.f) ? t3 : 0.f;
        __builtin_nontemporal_store(o, (f4v*)(pout + (size_t)(tr0 + r) * WW + (tc0 + c4)));
    }
}

extern "C" void kernel_launch(void* const* d_in, const int* in_sizes, int n_in,
                              void* d_out, int out_size, void* d_ws, size_t ws_size,
                              hipStream_t stream) {
    const float* x = (const float*)d_in[0];
    float* out = (float*)d_out;
    int n = in_sizes[0];                    // 8388608
    uint32_t* hist = (uint32_t*)d_ws;       // 4096*16 u32 (slot-major spread)
    uint32_t* state = hist + MAXBINS * HSPREAD;  // 8 u32
    uint32_t* cand = state + 8;             // candidates (mapped u32)
    uint32_t k = (uint32_t)((n - 1) / 2);
    int nvec = n / 4;

    init_kernel<<<(MAXBINS * HSPREAD + 255) / 256, 256, 0, stream>>>(hist, state, k);
    hist_kernel<<<HIST_GRID, HIST_BLOCK, 0, stream>>>((const uint4*)x, nvec, hist);
    select_kernel<<<1, 256, 0, stream>>>(hist, state);
    compact_kernel<<<COMP_GRID, HIST_BLOCK, 0, stream>>>((const uint4*)x, nvec, cand, state);
    final_select_kernel<<<1, 1024, 0, stream>>>(cand, state);

    int nplanes = n / (HH * WW);            // 2
    dim3 grid(WW / TILE_W, HH / TILE_H, nplanes);
    nms_kernel<<<grid, 256, 0, stream>>>(x, out, state);
}